// Round 7
// baseline (945.752 us; speedup 1.0000x reference)
//
#include <hip/hip_runtime.h>
#include <math.h>

#define N_ATOMS 60000
#define M_NBR   12
#define D_FEA   64
#define NBR_FEA 41
#define B_CRY   1200
#define NA_CRY  50
#define EPSV    1e-5f

#define NBLK_MAIN 2048   // blocks for k_stats / k_reduce (4 waves each)

__device__ __forceinline__ float wsum(float v){
#pragma unroll
  for (int o = 32; o > 0; o >>= 1) v += __shfl_xor(v, o, 64);
  return v;
}
__device__ __forceinline__ float wmax64(float v){
#pragma unroll
  for (int o = 32; o > 0; o >>= 1) v = fmaxf(v, __shfl_xor(v, o, 64));
  return v;
}
__device__ __forceinline__ float softplusf(float x){
  return fmaxf(x, 0.f) + __logf(1.f + __expf(-fabsf(x)));
}
__device__ __forceinline__ float sigmoidf(float x){
  return 1.f / (1.f + __expf(-x));
}
// round-to-nearest-even fp32 -> bf16 bits (low 16)
__device__ __forceinline__ unsigned bf16_rne(float x){
  unsigned u = __float_as_uint(x);
  return (u + 0x7fffu + ((u >> 16) & 1u)) >> 16;
}
__device__ __forceinline__ unsigned pack2(float lo, float hi){
  return bf16_rne(lo) | (bf16_rne(hi) << 16);
}
__device__ __forceinline__ float unlo(unsigned u){ return __uint_as_float(u << 16); }
__device__ __forceinline__ float unhi(unsigned u){ return __uint_as_float(u & 0xffff0000u); }

// ---------------- K1: per-crystal graph transformer -> atom_tf [N,64] -------
// 3 aliased LDS buffers (38.9 KiB -> 4 blocks/CU). Latency fixes (r6):
// phase 4 needs NO inner barriers (phase 2's reads of s_b ended at a
// barrier); unroll 2 on shfl-reduction row loops to overlap two 300-cycle
// bpermute chains.
__global__ __launch_bounds__(256, 4) void k_transformer(
    const float* __restrict__ atom_in, const float* __restrict__ adj,
    const float* __restrict__ w1, const float* __restrict__ b1,
    const float* __restrict__ w2, const float* __restrict__ b2,
    const float* __restrict__ g1v, const float* __restrict__ be1,
    const float* __restrict__ g2v, const float* __restrict__ be2,
    const int* __restrict__ cidx, float* __restrict__ atom_tf)
{
  __shared__ float s_a[NA_CRY * D_FEA];        // src / LN1(src)
  __shared__ float s_b[D_FEA * (NA_CRY + 1)];  // srcT(stride 51) / x / LN2-in
  __shared__ float s_c[NA_CRY * D_FEA];        // scores / h1

  const int tid  = threadIdx.x;
  const int b    = blockIdx.x;
  const int lane = tid & 63;
  const int w    = tid >> 6;

  // phase 1: load src (gather) + transposed copy (stride 51)
  for (int p = tid; p < NA_CRY * D_FEA; p += 256){
    int i = p >> 6, d = p & 63;
    int a = cidx[b * NA_CRY + i];
    float v = atom_in[a * D_FEA + d];
    s_a[p] = v;
    s_b[d * (NA_CRY + 1) + i] = v;
  }
  __syncthreads();

  // phase 2: scores = (src . src^T) * scale * adj  -> s_c[0:2500]
  const float scale = 0.125f; // 1/sqrt(64)
  for (int p = tid; p < NA_CRY * NA_CRY; p += 256){
    int i = p / NA_CRY;
    int jj = p - i * NA_CRY;
    float acc = 0.f;
#pragma unroll 8
    for (int d = 0; d < D_FEA; ++d)
      acc += s_a[i * D_FEA + d] * s_b[d * (NA_CRY + 1) + jj];
    s_c[p] = acc * scale * adj[b * NA_CRY * NA_CRY + p];
  }
  __syncthreads();

  // phase 3: softmax over rows (wave per row; unroll 2 -> two chains in ILP)
#pragma unroll 2
  for (int r = w; r < NA_CRY; r += 4){
    float v = (lane < NA_CRY) ? s_c[r * NA_CRY + lane] : -1e30f;
    float mx = wmax64(v);
    float e = (lane < NA_CRY) ? __expf(v - mx) : 0.f;
    float s = wsum(e);
    if (lane < NA_CRY) s_c[r * NA_CRY + lane] = e / s;
  }
  __syncthreads();

  // phase 4: x = src + attn @ src -> s_b (srcT dead; no inner barriers)
  for (int p = tid; p < NA_CRY * D_FEA; p += 256){
    int n = p >> 6, d = p & 63;
    float acc = 0.f;
#pragma unroll 10
    for (int m = 0; m < NA_CRY; ++m)
      acc += s_c[n * NA_CRY + m] * s_a[m * D_FEA + d];
    s_b[p] = s_a[p] + acc;
  }
  __syncthreads();

  // phase 5: LN1 -> s_a
#pragma unroll 2
  for (int r = w; r < NA_CRY; r += 4){
    float x = s_b[r * D_FEA + lane];
    float mu = wsum(x) * (1.f / 64.f);
    float dx = x - mu;
    float var = wsum(dx * dx) * (1.f / 64.f);
    s_a[r * D_FEA + lane] = dx * rsqrtf(var + EPSV) * g1v[lane] + be1[lane];
  }
  __syncthreads();

  // phase 6: h1 = relu(LN1 @ w1 + b1) -> s_c (scores dead)
  for (int p = tid; p < NA_CRY * D_FEA; p += 256){
    int n = p >> 6, d = p & 63;
    float acc = b1[d];
#pragma unroll 8
    for (int k = 0; k < D_FEA; ++k)
      acc += s_a[n * D_FEA + k] * w1[k * D_FEA + d];
    s_c[p] = fmaxf(acc, 0.f);
  }
  __syncthreads();

  // phase 7: t = LN1 + h1 @ w2 + b2 -> s_b
  for (int p = tid; p < NA_CRY * D_FEA; p += 256){
    int n = p >> 6, d = p & 63;
    float acc = b2[d];
#pragma unroll 8
    for (int k = 0; k < D_FEA; ++k)
      acc += s_c[n * D_FEA + k] * w2[k * D_FEA + d];
    s_b[p] = s_a[p] + acc;
  }
  __syncthreads();

  // phase 8: LN2 -> atom_tf
#pragma unroll 2
  for (int r = w; r < NA_CRY; r += 4){
    float x = s_b[r * D_FEA + lane];
    float mu = wsum(x) * (1.f / 64.f);
    float dx = x - mu;
    float var = wsum(dx * dx) * (1.f / 64.f);
    atom_tf[(b * NA_CRY + r) * D_FEA + lane] =
        dx * rsqrtf(var + EPSV) * g2v[lane] + be2[lane];
  }
}

// ---------------- K2: proj1p/proj2p packed bf16-pair outputs ----------------
// proj1p[a*64+l] = pack(bias+atom_tf@W[:,l], bias+atom_tf@W[:,l+64])
// proj2p[a*64+l] = pack(atom_in@W2[:,l], atom_in@W2[:,l+64])
// -> each gathered row is ONE coalesced 256B cache line (was 2x512B fp32).
__global__ __launch_bounds__(256) void k_proj(
    const float* __restrict__ atom_in, const float* __restrict__ atom_tf,
    const float* __restrict__ fc_w, const float* __restrict__ fc_b,
    unsigned* __restrict__ proj1p, unsigned* __restrict__ proj2p)
{
  __shared__ float sW1[64 * 128];
  __shared__ float sW2[64 * 128];
  const int tid = threadIdx.x, lane = tid & 63, w = tid >> 6;
  for (int p = tid; p < 64 * 128; p += 256){
    sW1[p] = fc_w[p];
    sW2[p] = fc_w[64 * 128 + p];
  }
  __syncthreads();
  const float bias0 = fc_b[lane], bias1 = fc_b[64 + lane];
  const int wg = blockIdx.x * 4 + w, nw = gridDim.x * 4;
  for (int a = wg; a < N_ATOMS; a += nw){
    float t1 = atom_tf[a * 64 + lane];
    float t2 = atom_in[a * 64 + lane];
    float p10 = bias0, p11 = bias1, p20 = 0.f, p21 = 0.f;
#pragma unroll
    for (int k = 0; k < 64; ++k){
      float a1 = __shfl(t1, k, 64);
      float a2 = __shfl(t2, k, 64);
      p10 += a1 * sW1[k * 128 + lane];
      p11 += a1 * sW1[k * 128 + 64 + lane];
      p20 += a2 * sW2[k * 128 + lane];
      p21 += a2 * sW2[k * 128 + 64 + lane];
    }
    proj1p[a * 64 + lane] = pack2(p10, p11);
    proj2p[a * 64 + lane] = pack2(p20, p21);
  }
}

// ---------------- K3: BN1 stats pass; optionally stores pre-BN g (bf16x2) ---
// 2-deep index prefetch + 1-deep row prefetch hides the L3 gather under the
// 41-FMA body. Weights live as 41 packed u32 VGPRs (proven r5).
template<int STORE>
__global__ __launch_bounds__(256) void k_stats(
    const float* __restrict__ nbr_fea, const int* __restrict__ nbr_idx,
    const float* __restrict__ fc_w, const unsigned* __restrict__ proj1p,
    const unsigned* __restrict__ proj2p, float* __restrict__ part1,
    unsigned* __restrict__ gated)
{
  __shared__ float red[1024];
  const int tid = threadIdx.x, lane = tid & 63, w = tid >> 6;

  unsigned wbp[NBR_FEA];
#pragma unroll
  for (int k = 0; k < NBR_FEA; ++k){
    float w0 = fc_w[(128 + k) * 128 + lane];
    float w1 = fc_w[(128 + k) * 128 + 64 + lane];
    wbp[k] = pack2(w0, w1);
  }

  const int wg = blockIdx.x * 4 + w, nw = gridDim.x * 4;
  float s0 = 0.f, s1 = 0.f, q0 = 0.f, q1 = 0.f;
  for (int a = wg; a < N_ATOMS; a += nw){
    const int au = __builtin_amdgcn_readfirstlane(a);
    const int base = au * M_NBR;
    unsigned p1v = proj1p[(size_t)au * 64 + lane];
    const float p10 = unlo(p1v), p11 = unhi(p1v);
    int jA = nbr_idx[base];                       // idx m
    int jB = nbr_idx[base + 1];                   // idx m+1
    unsigned rowN = proj2p[(size_t)__builtin_amdgcn_readfirstlane(jA) * 64 + lane];
#pragma unroll 1
    for (int m = 0; m < M_NBR; ++m){
      const unsigned row = rowN;
      const int r = base + m;
      const int jBu = __builtin_amdgcn_readfirstlane(jB);
      if (m + 2 < M_NBR) jB = nbr_idx[r + 2];     // idx 2 ahead
      if (m + 1 < M_NBR)                          // row 1 ahead
        rowN = proj2p[(size_t)jBu * 64 + lane];
      else { jB = jBu; }                          // keep shape; dead
      const float* frow = nbr_fea + (size_t)r * NBR_FEA;  // uniform -> s_load
      float g0 = p10 + unlo(row);
      float g1 = p11 + unhi(row);
#pragma unroll
      for (int k = 0; k < NBR_FEA; ++k){
        float aa = frow[k];
        g0 += aa * unlo(wbp[k]);
        g1 += aa * unhi(wbp[k]);
      }
      if (STORE) gated[(size_t)r * 64 + lane] = pack2(g0, g1);
      s0 += g0; q0 += g0 * g0;
      s1 += g1; q1 += g1 * g1;
    }
  }
  red[w * 256 + lane]        = s0;
  red[w * 256 + 64 + lane]   = s1;
  red[w * 256 + 128 + lane]  = q0;
  red[w * 256 + 192 + lane]  = q1;
  __syncthreads();
  float v = red[tid] + red[256 + tid] + red[512 + tid] + red[768 + tid];
  part1[blockIdx.x * 256 + tid] = v;   // [0:128]=sum(ch), [128:256]=sumsq(ch)
}

// finish BN1 stats: stats1[c]=scale, stats1[128+c]=shift
__global__ __launch_bounds__(1024) void k_stats_fin(
    const float* __restrict__ part1, const float* __restrict__ bn1_g,
    const float* __restrict__ bn1_b, float* __restrict__ stats1)
{
  __shared__ float red2[4 * 256];
  __shared__ float col[256];
  const int tid = threadIdx.x;
  const int c = tid & 255, g = tid >> 8;  // 4 groups
  float v = 0.f;
  for (int b = g; b < NBLK_MAIN; b += 4) v += part1[b * 256 + c];
  red2[g * 256 + c] = v;
  __syncthreads();
  if (g == 0) col[c] = red2[c] + red2[256 + c] + red2[512 + c] + red2[768 + c];
  __syncthreads();
  if (tid < 128){
    const float inv = 1.f / (float)(N_ATOMS * M_NBR);
    float mu = col[tid] * inv;
    float var = col[128 + tid] * inv - mu * mu;
    float sc = bn1_g[tid] * rsqrtf(var + EPSV);
    stats1[tid] = sc;
    stats1[128 + tid] = bn1_b[tid] - mu * sc;
  }
}

// ---------------- K4a (gated path): streaming BN1+gate+sum ------------------
__global__ __launch_bounds__(256) void k_reduce_g(
    const unsigned* __restrict__ gated, const float* __restrict__ stats1,
    float* __restrict__ nbr_sumed, float* __restrict__ part2)
{
  __shared__ float red[512];
  const int tid = threadIdx.x, lane = tid & 63, w = tid >> 6;
  const float sc0 = stats1[lane],       sc1 = stats1[64 + lane];
  const float tc0 = stats1[128 + lane], tc1 = stats1[192 + lane];
  const int wg = blockIdx.x * 4 + w, nw = gridDim.x * 4;
  float bs = 0.f, bq = 0.f;
  for (int a = wg; a < N_ATOMS; a += nw){
    const size_t base = (size_t)a * M_NBR * 64 + lane;
    float acc = 0.f;
#pragma unroll
    for (int m = 0; m < M_NBR; ++m){
      unsigned gv = gated[base + m * 64];
      acc += sigmoidf(unlo(gv) * sc0 + tc0) * softplusf(unhi(gv) * sc1 + tc1);
    }
    nbr_sumed[(size_t)a * 64 + lane] = acc;
    bs += acc; bq += acc * acc;
  }
  red[w * 128 + lane]      = bs;
  red[w * 128 + 64 + lane] = bq;
  __syncthreads();
  if (tid < 128){
    float v = red[tid] + red[128 + tid] + red[256 + tid] + red[384 + tid];
    part2[blockIdx.x * 128 + tid] = v;  // [0:64]=sum, [64:128]=sumsq
  }
}

// ---------------- K4b (fallback): recompute g, BN1, gate, sum ---------------
__global__ __launch_bounds__(256) void k_reduce_r(
    const float* __restrict__ nbr_fea, const int* __restrict__ nbr_idx,
    const float* __restrict__ fc_w, const unsigned* __restrict__ proj1p,
    const unsigned* __restrict__ proj2p, const float* __restrict__ stats1,
    float* __restrict__ nbr_sumed, float* __restrict__ part2)
{
  __shared__ float red[512];
  const int tid = threadIdx.x, lane = tid & 63, w = tid >> 6;
  unsigned wbp[NBR_FEA];
#pragma unroll
  for (int k = 0; k < NBR_FEA; ++k){
    float w0 = fc_w[(128 + k) * 128 + lane];
    float w1 = fc_w[(128 + k) * 128 + 64 + lane];
    wbp[k] = pack2(w0, w1);
  }
  const float sc0 = stats1[lane],       sc1 = stats1[64 + lane];
  const float tc0 = stats1[128 + lane], tc1 = stats1[192 + lane];
  const int wg = blockIdx.x * 4 + w, nw = gridDim.x * 4;
  float bs = 0.f, bq = 0.f;
  for (int a = wg; a < N_ATOMS; a += nw){
    const int au = __builtin_amdgcn_readfirstlane(a);
    const int base = au * M_NBR;
    unsigned p1v = proj1p[(size_t)au * 64 + lane];
    const float p10 = unlo(p1v), p11 = unhi(p1v);
    float acc = 0.f;
    int jA = nbr_idx[base];
    int jB = nbr_idx[base + 1];
    unsigned rowN = proj2p[(size_t)__builtin_amdgcn_readfirstlane(jA) * 64 + lane];
#pragma unroll 1
    for (int m = 0; m < M_NBR; ++m){
      const unsigned row = rowN;
      const int r = base + m;
      const int jBu = __builtin_amdgcn_readfirstlane(jB);
      if (m + 2 < M_NBR) jB = nbr_idx[r + 2];
      if (m + 1 < M_NBR) rowN = proj2p[(size_t)jBu * 64 + lane];
      const float* frow = nbr_fea + (size_t)r * NBR_FEA;
      float g0 = p10 + unlo(row);
      float g1 = p11 + unhi(row);
#pragma unroll
      for (int k = 0; k < NBR_FEA; ++k){
        float aa = frow[k];
        g0 += aa * unlo(wbp[k]);
        g1 += aa * unhi(wbp[k]);
      }
      acc += sigmoidf(g0 * sc0 + tc0) * softplusf(g1 * sc1 + tc1);
    }
    nbr_sumed[(size_t)a * 64 + lane] = acc;
    bs += acc; bq += acc * acc;
  }
  red[w * 128 + lane]      = bs;
  red[w * 128 + 64 + lane] = bq;
  __syncthreads();
  if (tid < 128){
    float v = red[tid] + red[128 + tid] + red[256 + tid] + red[384 + tid];
    part2[blockIdx.x * 128 + tid] = v;
  }
}

// finish BN2 stats
__global__ __launch_bounds__(1024) void k_red_fin(
    const float* __restrict__ part2, const float* __restrict__ bn2_g,
    const float* __restrict__ bn2_b, float* __restrict__ stats2)
{
  __shared__ float red2[8 * 128];
  __shared__ float col[128];
  const int tid = threadIdx.x;
  const int c = tid & 127, g = tid >> 7;  // 8 groups
  float v = 0.f;
  for (int b = g; b < NBLK_MAIN; b += 8) v += part2[b * 128 + c];
  red2[g * 128 + c] = v;
  __syncthreads();
  if (g == 0){
    float t = 0.f;
#pragma unroll
    for (int gg = 0; gg < 8; ++gg) t += red2[gg * 128 + c];
    col[c] = t;
  }
  __syncthreads();
  if (tid < 64){
    const float inv = 1.f / (float)N_ATOMS;
    float mu = col[tid] * inv;
    float var = col[64 + tid] * inv - mu * mu;
    float sc = bn2_g[tid] * rsqrtf(var + EPSV);
    stats2[tid] = sc;
    stats2[64 + tid] = bn2_b[tid] - mu * sc;
  }
}

// ---------------- K5: out = softplus(atom_tf + BN2(nbr_sumed)) --------------
__global__ __launch_bounds__(256) void k_final(
    const float* __restrict__ atom_tf, const float* __restrict__ ns,
    const float* __restrict__ stats2, float* __restrict__ out)
{
  int i = blockIdx.x * 256 + threadIdx.x;
  if (i >= N_ATOMS * 64) return;
  int c = i & 63;
  float x = atom_tf[i] + ns[i] * stats2[c] + stats2[64 + c];
  out[i] = softplusf(x);
}

extern "C" void kernel_launch(void* const* d_in, const int* in_sizes, int n_in,
                              void* d_out, int out_size, void* d_ws, size_t ws_size,
                              hipStream_t stream)
{
  const float* atom_in = (const float*)d_in[0];
  const float* nbr_fea = (const float*)d_in[1];
  const float* adj     = (const float*)d_in[2];
  const float* w1 = (const float*)d_in[3];
  const float* b1 = (const float*)d_in[4];
  const float* w2 = (const float*)d_in[5];
  const float* b2 = (const float*)d_in[6];
  const float* tln1_g = (const float*)d_in[7];
  const float* tln1_b = (const float*)d_in[8];
  const float* tln2_g = (const float*)d_in[9];
  const float* tln2_b = (const float*)d_in[10];
  const float* fc_w = (const float*)d_in[11];
  const float* fc_b = (const float*)d_in[12];
  const float* bn1_g = (const float*)d_in[13];
  const float* bn1_b = (const float*)d_in[14];
  const float* bn2_g = (const float*)d_in[15];
  const float* bn2_b = (const float*)d_in[16];
  const int* nbr_idx = (const int*)d_in[17];
  const int* cidx    = (const int*)d_in[18];
  float* out = (float*)d_out;

  char* ws = (char*)d_ws;
  size_t off = 0;
  float* atom_tf = (float*)(ws + off);    off += (size_t)N_ATOMS * 64 * 4;
  unsigned* proj1p = (unsigned*)(ws + off); off += (size_t)N_ATOMS * 64 * 4;
  unsigned* proj2p = (unsigned*)(ws + off); off += (size_t)N_ATOMS * 64 * 4;
  float* nbr_sumed = (float*)(ws + off);  off += (size_t)N_ATOMS * 64 * 4;
  float* part1 = (float*)(ws + off);      off += (size_t)NBLK_MAIN * 256 * 4;
  float* stats1 = (float*)(ws + off);     off += 256 * 4;
  float* part2 = (float*)(ws + off);      off += (size_t)NBLK_MAIN * 128 * 4;
  float* stats2 = (float*)(ws + off);     off += 128 * 4;
  unsigned* gated = (unsigned*)(ws + off);
  const size_t need_gated = off + (size_t)N_ATOMS * M_NBR * 64 * 4;
  const bool use_gated = (ws_size >= need_gated);

  k_transformer<<<B_CRY, 256, 0, stream>>>(atom_in, adj, w1, b1, w2, b2,
      tln1_g, tln1_b, tln2_g, tln2_b, cidx, atom_tf);
  k_proj<<<1024, 256, 0, stream>>>(atom_in, atom_tf, fc_w, fc_b, proj1p, proj2p);
  if (use_gated){
    k_stats<1><<<NBLK_MAIN, 256, 0, stream>>>(nbr_fea, nbr_idx, fc_w, proj1p,
        proj2p, part1, gated);
    k_stats_fin<<<1, 1024, 0, stream>>>(part1, bn1_g, bn1_b, stats1);
    k_reduce_g<<<NBLK_MAIN, 256, 0, stream>>>(gated, stats1, nbr_sumed, part2);
  } else {
    k_stats<0><<<NBLK_MAIN, 256, 0, stream>>>(nbr_fea, nbr_idx, fc_w, proj1p,
        proj2p, part1, gated);
    k_stats_fin<<<1, 1024, 0, stream>>>(part1, bn1_g, bn1_b, stats1);
    k_reduce_r<<<NBLK_MAIN, 256, 0, stream>>>(nbr_fea, nbr_idx, fc_w, proj1p,
        proj2p, stats1, nbr_sumed, part2);
  }
  k_red_fin<<<1, 1024, 0, stream>>>(part2, bn2_g, bn2_b, stats2);
  k_final<<<(N_ATOMS * 64 + 255) / 256, 256, 0, stream>>>(atom_tf, nbr_sumed, stats2, out);
}